// Round 1
// baseline (305.422 us; speedup 1.0000x reference)
//
#include <hip/hip_runtime.h>
#include <math.h>

// SPINN thin-stack encoder, B=64, L=128, D=128, T=255.
// Phase A (parallel): G[b,l,:] = buf[b,l,:] @ Wr  (right-operand transform of
//   every token, off the critical path).
// Phase B (sequential, 1 block per example): general shift-reduce machine.
//   Critical path per REDUCE: h @ Wl with Wl columns register-resident.

namespace {

constexpr int kB = 64;
constexpr int kL = 128;
constexpr int kD = 128;
constexpr int kT = 2 * kL - 1;  // 255
constexpr int kSlots = 150;     // fresh LDS slot per reduce (127 needed)
constexpr unsigned kRecZero = 0xFFFFFFFFu;  // initial zero-pad entries
constexpr unsigned kRecTok = 0x80000000u;   // token marker | token index
constexpr int kRowsPerBlk = 16;

// ---------------------------------------------------------------------------
// Phase A: G = buf @ Wr.   grid = B*L/kRowsPerBlk blocks x 128 threads.
// Thread d holds Wr[:,d] in 128 VGPRs; buf rows staged in LDS, read as
// broadcast float4.
// ---------------------------------------------------------------------------
__global__ __launch_bounds__(128) void precomp_wr_kernel(
    const float* __restrict__ buf, const float* __restrict__ Wr,
    float* __restrict__ G) {
  __shared__ float rows[kRowsPerBlk][kD];
  const int d = threadIdx.x;
  const long row0 = (long)blockIdx.x * kRowsPerBlk;

  float w[kD];
#pragma unroll
  for (int k = 0; k < kD; ++k) w[k] = Wr[k * kD + d];

  const float* src = buf + row0 * kD;
#pragma unroll
  for (int i = 0; i < kRowsPerBlk; ++i) rows[i][d] = src[i * kD + d];
  __syncthreads();

#pragma unroll
  for (int r = 0; r < kRowsPerBlk; ++r) {
    float acc = 0.f;
#pragma unroll
    for (int k4 = 0; k4 < kD / 4; ++k4) {
      const float4 x = *reinterpret_cast<const float4*>(&rows[r][k4 * 4]);
      acc = fmaf(x.x, w[k4 * 4 + 0], acc);
      acc = fmaf(x.y, w[k4 * 4 + 1], acc);
      acc = fmaf(x.z, w[k4 * 4 + 2], acc);
      acc = fmaf(x.w, w[k4 * 4 + 3], acc);
    }
    G[(row0 + r) * kD + d] = acc;
  }
}

// ---------------------------------------------------------------------------
// Phase B: sequential shift-reduce. grid = 64 blocks x 128 threads.
// Records for stack entries: kRecZero (initial pads), kRecTok|idx (token),
// else composed-slot index into stk[].
// rtop/rsec live in uniform registers; deeper records spill to the `deep`
// LDS array via replicated identical writes (race-free: every lane writes
// the same value, every wave observes at least its own write).
// Composed vectors get a FRESH stk slot each reduce -> the only cross-wave
// hazard is "write slot r, read slot r next step", covered by one
// __syncthreads() per reduce. SHIFT/SKIP need no barrier.
// ---------------------------------------------------------------------------
__global__ __launch_bounds__(128) void spinn_kernel(
    const float* __restrict__ buf, const float* __restrict__ Wl,
    const float* __restrict__ Wr, const float* __restrict__ bias,
    const int* __restrict__ trans, const float* __restrict__ G,
    float* __restrict__ out) {
  __shared__ float stk[kSlots][kD];
  __shared__ int tlds[kT];
  __shared__ unsigned deep[kT + 8];

  const int b = blockIdx.x;
  const int d = threadIdx.x;

  // Wl column d -> 128 VGPRs (the sequential-chain weight).
  float wl[kD];
#pragma unroll
  for (int k = 0; k < kD; ++k) wl[k] = Wl[k * kD + d];
  const float bv = bias[d];

  for (int t = d; t < kT; t += 128) tlds[t] = trans[b * kT + t];
  __syncthreads();

  const float* bufb = buf + (long)b * kL * kD;
  const float* Gb = (G != nullptr) ? (G + (long)b * kL * kD) : nullptr;

  unsigned rtop = kRecZero, rsec = kRecZero;
  int sp = 2, bp = 0, nxt = 0;

  for (int t = 0; t < kT; ++t) {
    const int tr = tlds[t];  // uniform broadcast read
    if (tr == 0) {
      // ---- SHIFT: pure record bookkeeping, no vector copy, no barrier ----
      deep[max(sp - 2, 0)] = rsec;  // replicated identical write
      rsec = rtop;
      rtop = kRecTok | (unsigned)min(bp, kL - 1);
      ++sp;
      ++bp;
    } else if (tr == 1) {
      // ---- REDUCE ----
      float acc = bv;

      // right operand (stack top): token -> precomputed G row (1 coalesced
      // load/thread, issued early so latency hides under the FMA loop).
      if (rtop != kRecZero) {
        if (rtop & kRecTok) {
          const unsigned tok = rtop & 0x7FFFFFFFu;
          if (Gb) {
            acc += Gb[(long)tok * kD + d];
          } else {  // ws too small fallback: direct mat-vec with global Wr
            const float* v = bufb + (long)tok * kD;
#pragma unroll 4
            for (int k = 0; k < kD; ++k)
              acc = fmaf(v[k], Wr[k * kD + d], acc);
          }
        } else {  // composed right (not hit by graded input)
          const float* v = stk[rtop];
#pragma unroll 4
          for (int k = 0; k < kD; ++k) acc = fmaf(v[k], Wr[k * kD + d], acc);
        }
      }

      // left operand (second): the recurrence. Register-resident Wl.
      if (rsec != kRecZero) {
        const float* v = (rsec & kRecTok)
                             ? (bufb + (long)(rsec & 0x7FFFFFFFu) * kD)
                             : stk[rsec];
#pragma unroll
        for (int k4 = 0; k4 < kD / 4; ++k4) {
          const float4 x = *reinterpret_cast<const float4*>(&v[k4 * 4]);
          acc = fmaf(x.x, wl[k4 * 4 + 0], acc);
          acc = fmaf(x.y, wl[k4 * 4 + 1], acc);
          acc = fmaf(x.z, wl[k4 * 4 + 2], acc);
          acc = fmaf(x.w, wl[k4 * 4 + 3], acc);
        }
      }

      const float y = tanhf(acc);

      const int slot = nxt;  // fresh slot, never aliases a live read
      ++nxt;
      if (nxt == kSlots) nxt = 0;  // wrap safety for pathological inputs
      stk[slot][d] = y;

      --sp;
      rtop = (unsigned)slot;
      rsec = deep[max(sp - 2, 0)];
      __syncthreads();  // publish stk[slot] before next step reads it
    }
    // tr == 2 (SKIP): no-op.
  }

  // Output = raw vector of the stack top.
  float o = 0.f;
  if (rtop != kRecZero) {
    o = (rtop & kRecTok) ? bufb[(long)(rtop & 0x7FFFFFFFu) * kD + d]
                         : stk[rtop][d];
  }
  out[(long)b * kD + d] = o;
}

}  // namespace

extern "C" void kernel_launch(void* const* d_in, const int* in_sizes, int n_in,
                              void* d_out, int out_size, void* d_ws,
                              size_t ws_size, hipStream_t stream) {
  const float* buf = (const float*)d_in[0];
  const float* Wl = (const float*)d_in[1];
  const float* Wr = (const float*)d_in[2];
  const float* bias = (const float*)d_in[3];
  const int* trans = (const int*)d_in[4];
  float* out = (float*)d_out;

  float* G = nullptr;
  const size_t gbytes = (size_t)kB * kL * kD * sizeof(float);
  if (ws_size >= gbytes) {
    G = (float*)d_ws;
    precomp_wr_kernel<<<dim3(kB * kL / kRowsPerBlk), dim3(128), 0, stream>>>(
        buf, Wr, G);
  }
  spinn_kernel<<<dim3(kB), dim3(128), 0, stream>>>(buf, Wl, Wr, bias, trans, G,
                                                   out);
}

// Round 2
// 216.728 us; speedup vs baseline: 1.4092x; 1.4092x over previous
//
#include <hip/hip_runtime.h>
#include <math.h>

// SPINN thin-stack encoder, B=64, L=128, D=128, T=255.
// Phase A (parallel): G[b,l,:] = buf[b,l,:] @ Wr  for every token.
// Phase B (sequential, 1 block per example): shift-reduce machine.
//   Per REDUCE critical path: h@Wl with Wl register-resident, 8-way split
//   accumulator chains; right operand from LDS-staged G; transitions
//   prefetched in int4 chunks; fast tanh via v_exp_f32.

namespace {

constexpr int kB = 64;
constexpr int kL = 128;
constexpr int kD = 128;
constexpr int kT = 2 * kL - 1;          // 255
constexpr int kTPad = 256;              // padded transition count (tail = SKIP)
constexpr int kSlots = 160;             // fresh LDS slot per reduce (127 used)
constexpr unsigned kRecZero = 0xFFFFFFFFu;
constexpr unsigned kRecTok = 0x80000000u;
constexpr unsigned kMask = 0x7FFFFFFFu;
constexpr int kRowsPerBlk = 16;

// ---------------------------------------------------------------------------
// Phase A: G = buf @ Wr.  grid = B*L/kRowsPerBlk x 128 threads.
// ---------------------------------------------------------------------------
__global__ __launch_bounds__(128) void precomp_wr_kernel(
    const float* __restrict__ buf, const float* __restrict__ Wr,
    float* __restrict__ G) {
  __shared__ float rows[kRowsPerBlk][kD];
  const int d = threadIdx.x;
  const long row0 = (long)blockIdx.x * kRowsPerBlk;

  float w[kD];
#pragma unroll
  for (int k = 0; k < kD; ++k) w[k] = Wr[k * kD + d];

  const float* src = buf + row0 * kD;
#pragma unroll
  for (int i = 0; i < kRowsPerBlk; ++i) rows[i][d] = src[i * kD + d];
  __syncthreads();

#pragma unroll
  for (int r = 0; r < kRowsPerBlk; ++r) {
    float a0 = 0.f, a1 = 0.f, a2 = 0.f, a3 = 0.f;
#pragma unroll
    for (int k4 = 0; k4 < kD / 4; ++k4) {
      const float4 x = *reinterpret_cast<const float4*>(&rows[r][k4 * 4]);
      a0 = fmaf(x.x, w[k4 * 4 + 0], a0);
      a1 = fmaf(x.y, w[k4 * 4 + 1], a1);
      a2 = fmaf(x.z, w[k4 * 4 + 2], a2);
      a3 = fmaf(x.w, w[k4 * 4 + 3], a3);
    }
    G[(row0 + r) * kD + d] = (a0 + a1) + (a2 + a3);
  }
}

__device__ __forceinline__ float fast_tanh(float x) {
  // tanh(x) = 1 - 2/(e^{2x}+1); saturates correctly at +-inf.
  const float e = __expf(2.0f * x);
  return 1.0f - 2.0f / (e + 1.0f);
}

// ---------------------------------------------------------------------------
// Phase B: grid = 64 blocks x 128 threads (2 waves).
// LDS: gl   = per-example G rows (right-operand transforms), 64 KB
//      stk  = composed vectors, fresh slot per reduce, 80 KB
//      tlds = transitions (padded to 256 with SKIP)
//      deep = record stack below top-2 (replicated identical writes)
// Records: kRecZero | (kRecTok|tokidx) | composed slot index.
// ---------------------------------------------------------------------------
__global__ __launch_bounds__(128) void spinn_kernel(
    const float* __restrict__ buf, const float* __restrict__ Wl,
    const float* __restrict__ Wr, const float* __restrict__ bias,
    const int* __restrict__ trans, const float* __restrict__ G,
    float* __restrict__ out) {
  __shared__ float gl[kL][kD];        // 65536 B
  __shared__ float stk[kSlots][kD];   // 81920 B
  __shared__ int tlds[kTPad];         // 1024 B
  __shared__ unsigned deep[kT + 8];   // 1052 B

  const int b = blockIdx.x;
  const int d = threadIdx.x;
  const bool useG = (G != nullptr);

  // Wl column d -> 128 VGPRs.
  float wl[kD];
#pragma unroll
  for (int k = 0; k < kD; ++k) wl[k] = Wl[k * kD + d];
  const float bv = bias[d];

  for (int t = d; t < kTPad; t += 128) tlds[t] = (t < kT) ? trans[b * kT + t] : 2;

  const float* bufb = buf + (long)b * kL * kD;

  // Stage this example's G into LDS (64 KB, coalesced float4).
  if (useG) {
    const float4* g4 = reinterpret_cast<const float4*>(G + (long)b * kL * kD);
    float4* l4 = reinterpret_cast<float4*>(&gl[0][0]);
#pragma unroll
    for (int i = 0; i < (kL * kD / 4) / 128; ++i) l4[i * 128 + d] = g4[i * 128 + d];
  }
  __syncthreads();

  unsigned rtop = kRecZero, rsec = kRecZero;
  int sp = 2, bp = 0, nxt = 0;

  int4 cur = *reinterpret_cast<const int4*>(&tlds[0]);
  for (int c = 0; c < kTPad / 4; ++c) {
    // Prefetch next chunk of transitions; consumed at chunk end, latency
    // hides under this chunk's reduce(s).
    int4 nxtv;
    if (c < kTPad / 4 - 1)
      nxtv = *reinterpret_cast<const int4*>(&tlds[(c + 1) * 4]);
    else
      nxtv = make_int4(2, 2, 2, 2);

    const int trs[4] = {cur.x, cur.y, cur.z, cur.w};
#pragma unroll
    for (int j = 0; j < 4; ++j) {
      const int tr = trs[j];
      if (tr == 0) {
        // ---- SHIFT: record bookkeeping only ----
        deep[max(sp - 2, 0)] = rsec;  // replicated identical write
        rsec = rtop;
        rtop = kRecTok | (unsigned)min(bp, kL - 1);
        ++sp;
        ++bp;
      } else if (tr == 1) {
        // ---- REDUCE ----
        float acc = bv;

        // Right operand (stack top).
        if (rtop != kRecZero) {
          if (rtop & kRecTok) {
            const int tok = (int)(rtop & kMask);
            if (useG) {
              acc += gl[tok][d];  // LDS read, issued early, hidden by left loop
            } else {
              const float* v = bufb + (long)tok * kD;
#pragma unroll 4
              for (int k = 0; k < kD; ++k) acc = fmaf(v[k], Wr[k * kD + d], acc);
            }
          } else {  // composed right (not hit by graded input)
            const float* v = stk[rtop];
#pragma unroll 4
            for (int k = 0; k < kD; ++k) acc = fmaf(v[k], Wr[k * kD + d], acc);
          }
        }

        // Left operand (stack second): the recurrence. 8-way acc split.
        float l0 = 0.f, l1 = 0.f, l2 = 0.f, l3 = 0.f;
        float l4 = 0.f, l5 = 0.f, l6 = 0.f, l7 = 0.f;
        if (rsec != kRecZero) {
          const float* v = (rsec & kRecTok)
                               ? (bufb + (long)(rsec & kMask) * kD)
                               : stk[rsec];
#pragma unroll
          for (int k8 = 0; k8 < kD / 8; ++k8) {
            const float4 xa = *reinterpret_cast<const float4*>(v + k8 * 8);
            const float4 xb = *reinterpret_cast<const float4*>(v + k8 * 8 + 4);
            l0 = fmaf(xa.x, wl[k8 * 8 + 0], l0);
            l1 = fmaf(xa.y, wl[k8 * 8 + 1], l1);
            l2 = fmaf(xa.z, wl[k8 * 8 + 2], l2);
            l3 = fmaf(xa.w, wl[k8 * 8 + 3], l3);
            l4 = fmaf(xb.x, wl[k8 * 8 + 4], l4);
            l5 = fmaf(xb.y, wl[k8 * 8 + 5], l5);
            l6 = fmaf(xb.z, wl[k8 * 8 + 6], l6);
            l7 = fmaf(xb.w, wl[k8 * 8 + 7], l7);
          }
        }
        acc += (((l0 + l1) + (l2 + l3)) + ((l4 + l5) + (l6 + l7)));

        const float y = fast_tanh(acc);

        const int slot = nxt;  // fresh slot; never aliases a live read
        ++nxt;
        if (nxt == kSlots) nxt = 0;
        stk[slot][d] = y;

        --sp;
        rtop = (unsigned)slot;
        rsec = deep[max(sp - 2, 0)];
        __syncthreads();  // publish stk[slot] for next step's readers
      }
      // tr == 2 (SKIP): no-op.
    }
    cur = nxtv;
  }

  float o = 0.f;
  if (rtop != kRecZero) {
    o = (rtop & kRecTok) ? bufb[(long)(rtop & kMask) * kD + d] : stk[rtop][d];
  }
  out[(long)b * kD + d] = o;
}

}  // namespace

extern "C" void kernel_launch(void* const* d_in, const int* in_sizes, int n_in,
                              void* d_out, int out_size, void* d_ws,
                              size_t ws_size, hipStream_t stream) {
  const float* buf = (const float*)d_in[0];
  const float* Wl = (const float*)d_in[1];
  const float* Wr = (const float*)d_in[2];
  const float* bias = (const float*)d_in[3];
  const int* trans = (const int*)d_in[4];
  float* out = (float*)d_out;

  float* G = nullptr;
  const size_t gbytes = (size_t)kB * kL * kD * sizeof(float);
  if (ws_size >= gbytes) {
    G = (float*)d_ws;
    precomp_wr_kernel<<<dim3(kB * kL / kRowsPerBlk), dim3(128), 0, stream>>>(
        buf, Wr, G);
  }
  spinn_kernel<<<dim3(kB), dim3(128), 0, stream>>>(buf, Wl, Wr, bias, trans, G,
                                                   out);
}

// Round 5
// 213.113 us; speedup vs baseline: 1.4331x; 1.0170x over previous
//
#include <hip/hip_runtime.h>
#include <math.h>

// SPINN thin-stack encoder, B=64, L=128, D=128, T=255.
// Phase A (parallel): G[b,l,:] = buf[b,l,:] @ Wr  for every token.
// Phase B (sequential, 1 block per example): shift-reduce machine.
//   Per REDUCE critical path: h@Wl with Wl columns REGISTER-resident
//   (launch_bounds(128,1) -> up to 512 VGPR/lane so wl[128] stays in regs),
//   8-way split accumulator chains; right operand from LDS-staged G;
//   transitions prefetched in int4 chunks; fast tanh via v_exp_f32.

namespace {

constexpr int kB = 64;
constexpr int kL = 128;
constexpr int kD = 128;
constexpr int kT = 2 * kL - 1;          // 255
constexpr int kTPad = 256;              // padded transition count (tail = SKIP)
constexpr int kSlots = 160;             // fresh LDS slot per reduce (127 used)
constexpr unsigned kRecZero = 0xFFFFFFFFu;
constexpr unsigned kRecTok = 0x80000000u;
constexpr unsigned kMask = 0x7FFFFFFFu;
constexpr int kRowsPerBlk = 16;

// ---------------------------------------------------------------------------
// Phase A: G = buf @ Wr.  grid = B*L/kRowsPerBlk x 128 threads.
// ---------------------------------------------------------------------------
__global__ __launch_bounds__(128, 1) void precomp_wr_kernel(
    const float* __restrict__ buf, const float* __restrict__ Wr,
    float* __restrict__ G) {
  __shared__ float rows[kRowsPerBlk][kD];
  const int d = threadIdx.x;
  const long row0 = (long)blockIdx.x * kRowsPerBlk;

  float w[kD];
#pragma unroll
  for (int k = 0; k < kD; ++k) w[k] = Wr[k * kD + d];

  const float* src = buf + row0 * kD;
#pragma unroll
  for (int i = 0; i < kRowsPerBlk; ++i) rows[i][d] = src[i * kD + d];
  __syncthreads();

#pragma unroll
  for (int r = 0; r < kRowsPerBlk; ++r) {
    float a0 = 0.f, a1 = 0.f, a2 = 0.f, a3 = 0.f;
#pragma unroll
    for (int k4 = 0; k4 < kD / 4; ++k4) {
      const float4 x = *reinterpret_cast<const float4*>(&rows[r][k4 * 4]);
      a0 = fmaf(x.x, w[k4 * 4 + 0], a0);
      a1 = fmaf(x.y, w[k4 * 4 + 1], a1);
      a2 = fmaf(x.z, w[k4 * 4 + 2], a2);
      a3 = fmaf(x.w, w[k4 * 4 + 3], a3);
    }
    G[(row0 + r) * kD + d] = (a0 + a1) + (a2 + a3);
  }
}

__device__ __forceinline__ float fast_tanh(float x) {
  // tanh(x) = 1 - 2/(e^{2x}+1); saturates correctly at +-inf.
  const float e = __expf(2.0f * x);
  return 1.0f - 2.0f / (e + 1.0f);
}

// ---------------------------------------------------------------------------
// Phase B: grid = 64 blocks x 128 threads (2 waves).
// LDS: gl   = per-example G rows (right-operand transforms), 64 KB
//      stk  = composed vectors, fresh slot per reduce, 80 KB
//      tlds = transitions (padded to 256 with SKIP)
//      deep = record stack below top-2 (replicated identical writes)
// Records: kRecZero | (kRecTok|tokidx) | composed slot index.
// launch_bounds(128,1): occupancy is irrelevant (64 blocks on 256 CUs);
// give the allocator the full register file so wl[128] never spills.
// ---------------------------------------------------------------------------
template <bool USE_G>
__global__ __launch_bounds__(128, 1) void spinn_kernel(
    const float* __restrict__ buf, const float* __restrict__ Wl,
    const float* __restrict__ Wr, const float* __restrict__ bias,
    const int* __restrict__ trans, const float* __restrict__ G,
    float* __restrict__ out) {
  __shared__ float gl[kL][kD];        // 65536 B
  __shared__ float stk[kSlots][kD];   // 81920 B
  __shared__ int tlds[kTPad];         // 1024 B
  __shared__ unsigned deep[kT + 8];   // 1052 B

  const int b = blockIdx.x;
  const int d = threadIdx.x;

  // Wl column d -> 128 VGPRs (register-resident across the whole recurrence).
  float wl[kD];
#pragma unroll
  for (int k = 0; k < kD; ++k) wl[k] = Wl[k * kD + d];
  const float bv = bias[d];

  for (int t = d; t < kTPad; t += 128) tlds[t] = (t < kT) ? trans[b * kT + t] : 2;

  const float* bufb = buf + (long)b * kL * kD;

  // Stage this example's G into LDS (64 KB, coalesced float4).
  if (USE_G) {
    const float4* g4 = reinterpret_cast<const float4*>(G + (long)b * kL * kD);
    float4* l4 = reinterpret_cast<float4*>(&gl[0][0]);
#pragma unroll
    for (int i = 0; i < (kL * kD / 4) / 128; ++i) l4[i * 128 + d] = g4[i * 128 + d];
  }
  __syncthreads();

  unsigned rtop = kRecZero, rsec = kRecZero;
  int sp = 2, bp = 0, nxt = 0;

  int4 cur = *reinterpret_cast<const int4*>(&tlds[0]);
  for (int c = 0; c < kTPad / 4; ++c) {
    // Prefetch next chunk of transitions; latency hides under this chunk.
    int4 nxtv;
    if (c < kTPad / 4 - 1)
      nxtv = *reinterpret_cast<const int4*>(&tlds[(c + 1) * 4]);
    else
      nxtv = make_int4(2, 2, 2, 2);

    const int trs[4] = {cur.x, cur.y, cur.z, cur.w};
#pragma unroll
    for (int j = 0; j < 4; ++j) {
      const int tr = trs[j];
      if (tr == 0) {
        // ---- SHIFT: record bookkeeping only ----
        deep[max(sp - 2, 0)] = rsec;  // replicated identical write
        rsec = rtop;
        rtop = kRecTok | (unsigned)min(bp, kL - 1);
        ++sp;
        ++bp;
      } else if (tr == 1) {
        // ---- REDUCE ----
        float acc = bv;

        // Right operand (stack top).
        if (__builtin_expect(rtop != kRecZero, 1)) {
          if (__builtin_expect((rtop & kRecTok) != 0, 1)) {
            const int tok = (int)(rtop & kMask);
            if (USE_G) {
              acc += gl[tok][d];  // LDS row read, hidden under left FMA loop
            } else {
              const float* v = bufb + (long)tok * kD;
              for (int k = 0; k < kD; ++k) acc = fmaf(v[k], Wr[k * kD + d], acc);
            }
          } else {  // composed right (never hit by graded input) - cold
            const float* v = stk[rtop];
            for (int k = 0; k < kD; ++k) acc = fmaf(v[k], Wr[k * kD + d], acc);
          }
        }

        // Left operand (stack second): the recurrence. 8-way acc split,
        // wl register-resident.
        float l0 = 0.f, l1 = 0.f, l2 = 0.f, l3 = 0.f;
        float l4 = 0.f, l5 = 0.f, l6 = 0.f, l7 = 0.f;
        if (__builtin_expect(rsec != kRecZero, 1)) {
          const float* v = (rsec & kRecTok)
                               ? (bufb + (long)(rsec & kMask) * kD)
                               : stk[rsec];
#pragma unroll
          for (int k8 = 0; k8 < kD / 8; ++k8) {
            const float4 xa = *reinterpret_cast<const float4*>(v + k8 * 8);
            const float4 xb = *reinterpret_cast<const float4*>(v + k8 * 8 + 4);
            l0 = fmaf(xa.x, wl[k8 * 8 + 0], l0);
            l1 = fmaf(xa.y, wl[k8 * 8 + 1], l1);
            l2 = fmaf(xa.z, wl[k8 * 8 + 2], l2);
            l3 = fmaf(xa.w, wl[k8 * 8 + 3], l3);
            l4 = fmaf(xb.x, wl[k8 * 8 + 4], l4);
            l5 = fmaf(xb.y, wl[k8 * 8 + 5], l5);
            l6 = fmaf(xb.z, wl[k8 * 8 + 6], l6);
            l7 = fmaf(xb.w, wl[k8 * 8 + 7], l7);
          }
        }
        acc += (((l0 + l1) + (l2 + l3)) + ((l4 + l5) + (l6 + l7)));

        const float y = fast_tanh(acc);

        const int slot = nxt;  // fresh slot; never aliases a live read
        ++nxt;
        if (nxt == kSlots) nxt = 0;
        stk[slot][d] = y;

        --sp;
        rtop = (unsigned)slot;
        rsec = deep[max(sp - 2, 0)];
        __syncthreads();  // publish stk[slot] for next step's readers
      }
      // tr == 2 (SKIP): no-op.
    }
    cur = nxtv;
  }

  float o = 0.f;
  if (rtop != kRecZero) {
    o = (rtop & kRecTok) ? bufb[(long)(rtop & kMask) * kD + d] : stk[rtop][d];
  }
  out[(long)b * kD + d] = o;
}

}  // namespace

extern "C" void kernel_launch(void* const* d_in, const int* in_sizes, int n_in,
                              void* d_out, int out_size, void* d_ws,
                              size_t ws_size, hipStream_t stream) {
  const float* buf = (const float*)d_in[0];
  const float* Wl = (const float*)d_in[1];
  const float* Wr = (const float*)d_in[2];
  const float* bias = (const float*)d_in[3];
  const int* trans = (const int*)d_in[4];
  float* out = (float*)d_out;

  const size_t gbytes = (size_t)kB * kL * kD * sizeof(float);
  if (ws_size >= gbytes) {
    float* G = (float*)d_ws;
    precomp_wr_kernel<<<dim3(kB * kL / kRowsPerBlk), dim3(128), 0, stream>>>(
        buf, Wr, G);
    spinn_kernel<true><<<dim3(kB), dim3(128), 0, stream>>>(buf, Wl, Wr, bias,
                                                           trans, G, out);
  } else {
    spinn_kernel<false><<<dim3(kB), dim3(128), 0, stream>>>(
        buf, Wl, Wr, bias, trans, nullptr, out);
  }
}

// Round 7
// 173.855 us; speedup vs baseline: 1.7568x; 1.2258x over previous
//
#include <hip/hip_runtime.h>
#include <math.h>

// SPINN thin-stack encoder, B=64, L=128, D=128, T=255.
// Phase A (parallel): G[b,l,:] = buf[b,l,:] @ Wr  for every token.
// Phase B (sequential, 1 block per example): shift-reduce machine.
//   Key fix this round: NO flat pointers. Left-operand loads are either
//   global_load_dwordx4 (token row of buf) or ds_read_b128 (stk row),
//   selected by an explicit uniform branch -- never a pointer select.
//   Stack records r0/r1/r2 live in registers with a write-through LDS
//   mirror (deep[]); the refill read is issued at reduce start so its
//   latency hides under the FMA loop.

namespace {

constexpr int kB = 64;
constexpr int kL = 128;
constexpr int kD = 128;
constexpr int kT = 2 * kL - 1;          // 255
constexpr int kTPad = 256;              // padded transitions (tail = SKIP)
constexpr int kSlots = 160;             // fresh LDS slot per reduce (127 used)
constexpr unsigned kRecZero = 0xFFFFFFFFu;
constexpr unsigned kRecTok = 0x80000000u;
constexpr unsigned kMask = 0x7FFFFFFFu;
constexpr int kRowsPerBlk = 16;

// ---------------------------------------------------------------------------
// Phase A: G = buf @ Wr.  grid = B*L/kRowsPerBlk x 128 threads.
// ---------------------------------------------------------------------------
__global__ __launch_bounds__(128, 1) void precomp_wr_kernel(
    const float* __restrict__ buf, const float* __restrict__ Wr,
    float* __restrict__ G) {
  __shared__ float rows[kRowsPerBlk][kD];
  const int d = threadIdx.x;
  const long row0 = (long)blockIdx.x * kRowsPerBlk;

  float w[kD];
#pragma unroll
  for (int k = 0; k < kD; ++k) w[k] = Wr[k * kD + d];

  const float* src = buf + row0 * kD;
#pragma unroll
  for (int i = 0; i < kRowsPerBlk; ++i) rows[i][d] = src[i * kD + d];
  __syncthreads();

#pragma unroll
  for (int r = 0; r < kRowsPerBlk; ++r) {
    float a0 = 0.f, a1 = 0.f, a2 = 0.f, a3 = 0.f;
#pragma unroll
    for (int k4 = 0; k4 < kD / 4; ++k4) {
      const float4 x = *reinterpret_cast<const float4*>(&rows[r][k4 * 4]);
      a0 = fmaf(x.x, w[k4 * 4 + 0], a0);
      a1 = fmaf(x.y, w[k4 * 4 + 1], a1);
      a2 = fmaf(x.z, w[k4 * 4 + 2], a2);
      a3 = fmaf(x.w, w[k4 * 4 + 3], a3);
    }
    G[(row0 + r) * kD + d] = (a0 + a1) + (a2 + a3);
  }
}

__device__ __forceinline__ float fast_tanh(float x) {
  // tanh(x) = 1 - 2/(e^{2x}+1); saturates correctly at +-inf.
  const float e = __expf(2.0f * x);
  return 1.0f - 2.0f / (e + 1.0f);
}

// ---------------------------------------------------------------------------
// Phase B: grid = 64 blocks x 128 threads (2 waves).
// LDS: gl   = per-example G rows (right-operand transforms), 64 KB
//      stk  = composed vectors, fresh slot per reduce, 80 KB
//      tlds = transitions (padded with SKIP)
//      deep = write-through mirror of ALL stack records (replicated
//             identical writes by every thread -> each wave sees its own
//             copy, no barrier needed for deep[]).
// Records: kRecZero | (kRecTok|tokidx) | composed slot index.
// Register window: r0 = top record, r1 = second, r2 = third.
// ---------------------------------------------------------------------------
template <bool USE_G>
__global__ __launch_bounds__(128, 1) void spinn_kernel(
    const float* __restrict__ buf, const float* __restrict__ Wl,
    const float* __restrict__ Wr, const float* __restrict__ bias,
    const int* __restrict__ trans, const float* __restrict__ G,
    float* __restrict__ out) {
  __shared__ float gl[kL][kD];        // 65536 B
  __shared__ float stk[kSlots][kD];   // 81920 B
  __shared__ int tlds[kTPad];         // 1024 B
  __shared__ unsigned deep[kT + 8];   // record mirror

  const int b = blockIdx.x;
  const int d = threadIdx.x;

  // Wl column d -> registers (used by every reduce).
  float wl[kD];
#pragma unroll
  for (int k = 0; k < kD; ++k) wl[k] = Wl[k * kD + d];
  const float bv = bias[d];

  for (int t = d; t < kTPad; t += 128) tlds[t] = (t < kT) ? trans[b * kT + t] : 2;
  deep[0] = kRecZero;  // two zero-pad entries (replicated writes)
  deep[1] = kRecZero;

  const float* bufb = buf + (long)b * kL * kD;

  // Stage this example's G into LDS (64 KB, coalesced float4).
  if (USE_G) {
    const float4* g4 = reinterpret_cast<const float4*>(G + (long)b * kL * kD);
    float4* l4 = reinterpret_cast<float4*>(&gl[0][0]);
#pragma unroll
    for (int i = 0; i < (kL * kD / 4) / 128; ++i) l4[i * 128 + d] = g4[i * 128 + d];
  }
  __syncthreads();

  unsigned r0 = kRecZero, r1 = kRecZero, r2 = kRecZero;
  int sp = 2, bp = 0, nxt = 0;

  int4 cur = *reinterpret_cast<const int4*>(&tlds[0]);
  for (int c = 0; c < kTPad / 4; ++c) {
    int4 nxtv;  // prefetch next transition chunk; latency hidden
    if (c < kTPad / 4 - 1)
      nxtv = *reinterpret_cast<const int4*>(&tlds[(c + 1) * 4]);
    else
      nxtv = make_int4(2, 2, 2, 2);

    const int trs[4] = {cur.x, cur.y, cur.z, cur.w};
#pragma unroll
    for (int j = 0; j < 4; ++j) {
      const int tr = trs[j];
      if (tr == 0) {
        // ---- SHIFT: register/record bookkeeping only ----
        const unsigned tokRec = kRecTok | (unsigned)min(bp, kL - 1);
        deep[sp] = tokRec;  // write-through mirror (replicated)
        r2 = r1;
        r1 = r0;
        r0 = tokRec;
        ++sp;
        ++bp;
      } else if (tr == 1) {
        // ---- REDUCE ----
        // Early refill: the record that becomes r2 after this pop.
        const unsigned refill = deep[max(sp - 4, 0)];

        float acc = bv;

        // Right operand = r0 (top). Hot path: token -> LDS-staged G row.
        if (__builtin_expect(r0 != kRecZero, 1)) {
          if (__builtin_expect((r0 & kRecTok) != 0, 1)) {
            const int tok = (int)(r0 & kMask);
            if (USE_G) {
              acc += gl[tok][d];  // ds_read, hidden under left FMA loop
            } else {
              const float* __restrict__ v = bufb + (long)tok * kD;
              for (int k = 0; k < kD; ++k) acc = fmaf(v[k], Wr[k * kD + d], acc);
            }
          } else {  // cold: composed right
            const int row = (int)r0;
            for (int k = 0; k < kD; ++k)
              acc = fmaf(stk[row][k], Wr[k * kD + d], acc);
          }
        }

        // Left operand = r1 (second): the recurrence. Two address-space-
        // clean loops -- NO pointer select, NO flat loads.
        float l0 = 0.f, l1 = 0.f, l2 = 0.f, l3 = 0.f;
        float l4 = 0.f, l5 = 0.f, l6 = 0.f, l7 = 0.f;
        if (__builtin_expect(r1 != kRecZero, 1)) {
          if (r1 & kRecTok) {
            // global path: token row of buf
            const float* __restrict__ v = bufb + (long)(r1 & kMask) * kD;
#pragma unroll
            for (int k8 = 0; k8 < kD / 8; ++k8) {
              const float4 xa = *reinterpret_cast<const float4*>(v + k8 * 8);
              const float4 xb = *reinterpret_cast<const float4*>(v + k8 * 8 + 4);
              l0 = fmaf(xa.x, wl[k8 * 8 + 0], l0);
              l1 = fmaf(xa.y, wl[k8 * 8 + 1], l1);
              l2 = fmaf(xa.z, wl[k8 * 8 + 2], l2);
              l3 = fmaf(xa.w, wl[k8 * 8 + 3], l3);
              l4 = fmaf(xb.x, wl[k8 * 8 + 4], l4);
              l5 = fmaf(xb.y, wl[k8 * 8 + 5], l5);
              l6 = fmaf(xb.z, wl[k8 * 8 + 6], l6);
              l7 = fmaf(xb.w, wl[k8 * 8 + 7], l7);
            }
          } else {
            // LDS path: composed row in stk -> ds_read_b128 broadcasts
            const int row = (int)r1;
#pragma unroll
            for (int k8 = 0; k8 < kD / 8; ++k8) {
              const float4 xa =
                  *reinterpret_cast<const float4*>(&stk[row][k8 * 8]);
              const float4 xb =
                  *reinterpret_cast<const float4*>(&stk[row][k8 * 8 + 4]);
              l0 = fmaf(xa.x, wl[k8 * 8 + 0], l0);
              l1 = fmaf(xa.y, wl[k8 * 8 + 1], l1);
              l2 = fmaf(xa.z, wl[k8 * 8 + 2], l2);
              l3 = fmaf(xa.w, wl[k8 * 8 + 3], l3);
              l4 = fmaf(xb.x, wl[k8 * 8 + 4], l4);
              l5 = fmaf(xb.y, wl[k8 * 8 + 5], l5);
              l6 = fmaf(xb.z, wl[k8 * 8 + 6], l6);
              l7 = fmaf(xb.w, wl[k8 * 8 + 7], l7);
            }
          }
        }
        acc += (((l0 + l1) + (l2 + l3)) + ((l4 + l5) + (l6 + l7)));

        const float y = fast_tanh(acc);

        const int slot = nxt;  // fresh slot; never aliases a live read
        ++nxt;
        if (nxt == kSlots) nxt = 0;
        stk[slot][d] = y;

        deep[sp - 2] = (unsigned)slot;  // write-through mirror (replicated)
        --sp;
        r0 = (unsigned)slot;
        r1 = r2;
        r2 = refill;  // waitcnt lands here, long after issue
        __syncthreads();  // publish stk[slot] for next step's readers
      }
      // tr == 2 (SKIP): no-op.
    }
    cur = nxtv;
  }

  float o = 0.f;
  if (r0 != kRecZero) {
    if (r0 & kRecTok)
      o = bufb[(long)(r0 & kMask) * kD + d];
    else
      o = stk[(int)r0][d];
  }
  out[(long)b * kD + d] = o;
}

}  // namespace

extern "C" void kernel_launch(void* const* d_in, const int* in_sizes, int n_in,
                              void* d_out, int out_size, void* d_ws,
                              size_t ws_size, hipStream_t stream) {
  const float* buf = (const float*)d_in[0];
  const float* Wl = (const float*)d_in[1];
  const float* Wr = (const float*)d_in[2];
  const float* bias = (const float*)d_in[3];
  const int* trans = (const int*)d_in[4];
  float* out = (float*)d_out;

  const size_t gbytes = (size_t)kB * kL * kD * sizeof(float);
  if (ws_size >= gbytes) {
    float* G = (float*)d_ws;
    precomp_wr_kernel<<<dim3(kB * kL / kRowsPerBlk), dim3(128), 0, stream>>>(
        buf, Wr, G);
    spinn_kernel<true><<<dim3(kB), dim3(128), 0, stream>>>(buf, Wl, Wr, bias,
                                                           trans, G, out);
  } else {
    spinn_kernel<false><<<dim3(kB), dim3(128), 0, stream>>>(
        buf, Wl, Wr, bias, trans, nullptr, out);
  }
}